// Round 4
// baseline (646.464 us; speedup 1.0000x reference)
//
#include <hip/hip_runtime.h>
#include <hip/hip_bf16.h>
#include <cmath>

#define N_NODES 100000
#define N_EDGES 1600000
#define IN_F 48
#define HID_F 16
#define OUT_F 60

#define BKT 128                                  // nodes per bucket
#define NBKT ((N_NODES + BKT - 1) / BKT)         // 782
#define EPB 2048                                 // edges per block (hist/partition)
#define NB_E2 ((N_EDGES + EPB - 1) / EPB)        // 782

typedef __hip_bfloat16 bf16;

// ---------------- CSR-less build: bucket counting sort ------------------------
__global__ __launch_bounds__(1024) void k_zero_b(int* __restrict__ bcnt)
{
    if (threadIdx.x < NBKT) bcnt[threadIdx.x] = 0;
}

__global__ __launch_bounds__(256) void k_bhist(
    const int* __restrict__ dst, int* __restrict__ bcnt)
{
    __shared__ int h[NBKT];
    for (int i = threadIdx.x; i < NBKT; i += 256) h[i] = 0;
    __syncthreads();
    int base = blockIdx.x * EPB;
    #pragma unroll
    for (int i = 0; i < EPB / 256; ++i) {
        int e = base + i * 256 + threadIdx.x;
        if (e < N_EDGES) atomicAdd(&h[dst[e] >> 7], 1);
    }
    __syncthreads();
    for (int i = threadIdx.x; i < NBKT; i += 256)
        if (h[i]) atomicAdd(&bcnt[i], h[i]);
}

// Exclusive scan of 782 bucket counts -> base[NBKT+1], cursor[NBKT].
__global__ __launch_bounds__(1024) void k_bscan(
    const int* __restrict__ bcnt, int* __restrict__ base, int* __restrict__ cursor)
{
    __shared__ int tmp[1024];
    int v = (threadIdx.x < NBKT) ? bcnt[threadIdx.x] : 0;
    tmp[threadIdx.x] = v;
    __syncthreads();
    #pragma unroll
    for (int ofs = 1; ofs < 1024; ofs <<= 1) {
        int a = (threadIdx.x >= ofs) ? tmp[threadIdx.x - ofs] : 0;
        __syncthreads();
        tmp[threadIdx.x] += a;
        __syncthreads();
    }
    if (threadIdx.x < NBKT) {
        int ex = tmp[threadIdx.x] - v;
        base[threadIdx.x] = ex;
        cursor[threadIdx.x] = ex;
    }
    if (threadIdx.x == 0) base[NBKT] = N_EDGES;
}

// Partition edges into dst-buckets; packed word = (src << 7) | (dst & 127).
__global__ __launch_bounds__(256) void k_partition(
    const int* __restrict__ src, const int* __restrict__ dst,
    int* __restrict__ cursor, unsigned int* __restrict__ pk)
{
    __shared__ int cnt[NBKT];
    __shared__ int bb[NBKT];
    for (int i = threadIdx.x; i < NBKT; i += 256) cnt[i] = 0;
    __syncthreads();
    int e0 = blockIdx.x * EPB;
    int dloc[EPB / 256];
    #pragma unroll
    for (int i = 0; i < EPB / 256; ++i) {
        int e = e0 + i * 256 + threadIdx.x;
        dloc[i] = (e < N_EDGES) ? dst[e] : -1;
        if (dloc[i] >= 0) atomicAdd(&cnt[dloc[i] >> 7], 1);
    }
    __syncthreads();
    for (int i = threadIdx.x; i < NBKT; i += 256) {
        int c = cnt[i];
        bb[i] = c ? atomicAdd(&cursor[i], c) : 0;
        cnt[i] = 0;
    }
    __syncthreads();
    #pragma unroll
    for (int i = 0; i < EPB / 256; ++i) {
        int e = e0 + i * 256 + threadIdx.x;
        int d = dloc[i];
        if (d >= 0) {
            int b = d >> 7;
            int r = atomicAdd(&cnt[b], 1);
            pk[bb[b] + r] = ((unsigned int)src[e] << 7) | (unsigned int)(d & 127);
        }
    }
}

// ---------------- Fused gather: P[bucket nodes] += sum Y[src] -----------------
// One block per bucket; LDS f32 accumulator [128][16]; 16 lanes per edge.
__global__ __launch_bounds__(256) void k_gather(
    const int* __restrict__ base, const unsigned int* __restrict__ pk,
    const bf16* __restrict__ Yh, float* __restrict__ P)
{
    __shared__ float acc[BKT * HID_F];   // 8 KB
    int b = blockIdx.x;
    int e0 = base[b], e1 = base[b + 1];
    for (int i = threadIdx.x; i < BKT * HID_F; i += 256) acc[i] = 0.f;
    __syncthreads();

    int lane = threadIdx.x & 15;
    int e = e0 + (threadIdx.x >> 4);
    // 4-way unrolled: 4 independent pk->Y load chains in flight
    for (; e + 48 < e1; e += 64) {
        unsigned int p0 = pk[e], p1 = pk[e + 16], p2 = pk[e + 32], p3 = pk[e + 48];
        float v0 = __bfloat162float(Yh[(size_t)(p0 >> 7) * HID_F + lane]);
        float v1 = __bfloat162float(Yh[(size_t)(p1 >> 7) * HID_F + lane]);
        float v2 = __bfloat162float(Yh[(size_t)(p2 >> 7) * HID_F + lane]);
        float v3 = __bfloat162float(Yh[(size_t)(p3 >> 7) * HID_F + lane]);
        atomicAdd(&acc[(p0 & 127u) * HID_F + lane], v0);
        atomicAdd(&acc[(p1 & 127u) * HID_F + lane], v1);
        atomicAdd(&acc[(p2 & 127u) * HID_F + lane], v2);
        atomicAdd(&acc[(p3 & 127u) * HID_F + lane], v3);
    }
    for (; e < e1; e += 16) {
        unsigned int p = pk[e];
        float v = __bfloat162float(Yh[(size_t)(p >> 7) * HID_F + lane]);
        atomicAdd(&acc[(p & 127u) * HID_F + lane], v);
    }
    __syncthreads();

    // Write out: 2048 floats; thread t -> node r=t>>1, half h=t&1 (2 float4 each)
    int r = threadIdx.x >> 1;
    int hq = threadIdx.x & 1;
    int n = b * BKT + r;
    if (n < N_NODES) {
        float4* pr = reinterpret_cast<float4*>(P + (size_t)n * HID_F) + hq * 2;
        const float4* ar = reinterpret_cast<const float4*>(acc + r * HID_F) + hq * 2;
        float4 a0 = ar[0], a1 = ar[1];
        float4 p0 = pr[0], p1 = pr[1];
        pr[0] = make_float4(p0.x + a0.x, p0.y + a0.y, p0.z + a0.z, p0.w + a0.w);
        pr[1] = make_float4(p1.x + a1.x, p1.y + a1.y, p1.z + a1.z, p1.w + a1.w);
    }
}

// ---------------- Layer-1: Yh = bf16(x@W1_rel), P = x@W1_root + b1 ------------
__global__ __launch_bounds__(256) void k1_lin48(
    const float* __restrict__ x, const float* __restrict__ Wrel,
    const float* __restrict__ b, const float* __restrict__ Wroot,
    bf16* __restrict__ Yh, float* __restrict__ P)
{
    __shared__ float sWrel[IN_F * HID_F];
    __shared__ float sWroot[IN_F * HID_F];
    __shared__ float sb[HID_F];
    for (int i = threadIdx.x; i < IN_F * HID_F; i += 256) {
        sWrel[i]  = Wrel[i];
        sWroot[i] = Wroot[i];
    }
    if (threadIdx.x < HID_F) sb[threadIdx.x] = b[threadIdx.x];
    __syncthreads();

    int n = blockIdx.x * 256 + threadIdx.x;
    if (n >= N_NODES) return;

    float xv[IN_F];
    const float4* xr = reinterpret_cast<const float4*>(x + (size_t)n * IN_F);
    #pragma unroll
    for (int i = 0; i < IN_F / 4; ++i) {
        float4 t = xr[i];
        xv[4*i+0] = t.x; xv[4*i+1] = t.y; xv[4*i+2] = t.z; xv[4*i+3] = t.w;
    }

    float accR[HID_F], accT[HID_F];
    #pragma unroll
    for (int f = 0; f < HID_F; ++f) { accR[f] = 0.0f; accT[f] = sb[f]; }

    #pragma unroll 6
    for (int k = 0; k < IN_F; ++k) {
        float xk = xv[k];
        #pragma unroll
        for (int f = 0; f < HID_F; ++f) {
            accR[f] = fmaf(xk, sWrel[k*HID_F + f], accR[f]);
            accT[f] = fmaf(xk, sWroot[k*HID_F + f], accT[f]);
        }
    }

    union { bf16 h[HID_F]; uint4 q[2]; } yo;
    #pragma unroll
    for (int f = 0; f < HID_F; ++f) yo.h[f] = __float2bfloat16(accR[f]);
    uint4* yq = reinterpret_cast<uint4*>(Yh + (size_t)n * HID_F);
    yq[0] = yo.q[0]; yq[1] = yo.q[1];

    float4* pr = reinterpret_cast<float4*>(P + (size_t)n * HID_F);
    #pragma unroll
    for (int q = 0; q < HID_F / 4; ++q)
        pr[q] = make_float4(accT[4*q], accT[4*q+1], accT[4*q+2], accT[4*q+3]);
}

// -------- Layer-2: h=tanh(P); Yh=bf16(h@Wrel); P=h@Wroot+b --------------------
__global__ __launch_bounds__(256) void k3_lin16(
    bf16* __restrict__ Yh, float* __restrict__ P,
    const float* __restrict__ Wrel, const float* __restrict__ b,
    const float* __restrict__ Wroot)
{
    __shared__ float sWrel[HID_F * HID_F];
    __shared__ float sWroot[HID_F * HID_F];
    __shared__ float sb[HID_F];
    if (threadIdx.x < HID_F * HID_F) {
        sWrel[threadIdx.x]  = Wrel[threadIdx.x];
        sWroot[threadIdx.x] = Wroot[threadIdx.x];
    }
    if (threadIdx.x < HID_F) sb[threadIdx.x] = b[threadIdx.x];
    __syncthreads();

    int n = blockIdx.x * 256 + threadIdx.x;
    if (n >= N_NODES) return;

    float h[HID_F];
    float4* pr = reinterpret_cast<float4*>(P + (size_t)n * HID_F);
    #pragma unroll
    for (int q = 0; q < HID_F / 4; ++q) {
        float4 t = pr[q];
        h[4*q+0] = tanhf(t.x); h[4*q+1] = tanhf(t.y);
        h[4*q+2] = tanhf(t.z); h[4*q+3] = tanhf(t.w);
    }

    float accR[HID_F], accT[HID_F];
    #pragma unroll
    for (int f = 0; f < HID_F; ++f) { accR[f] = 0.0f; accT[f] = sb[f]; }

    #pragma unroll
    for (int k = 0; k < HID_F; ++k) {
        float hk = h[k];
        #pragma unroll
        for (int f = 0; f < HID_F; ++f) {
            accR[f] = fmaf(hk, sWrel[k*HID_F + f], accR[f]);
            accT[f] = fmaf(hk, sWroot[k*HID_F + f], accT[f]);
        }
    }

    union { bf16 hh[HID_F]; uint4 q[2]; } yo;
    #pragma unroll
    for (int f = 0; f < HID_F; ++f) yo.hh[f] = __float2bfloat16(accR[f]);
    uint4* yq = reinterpret_cast<uint4*>(Yh + (size_t)n * HID_F);
    yq[0] = yo.q[0]; yq[1] = yo.q[1];

    #pragma unroll
    for (int q = 0; q < HID_F / 4; ++q)
        pr[q] = make_float4(accT[4*q], accT[4*q+1], accT[4*q+2], accT[4*q+3]);
}

// -------- Layer-3 prep: Yh = bf16(tanh(P)) (=h2), P = 0 -----------------------
__global__ __launch_bounds__(256) void k5_tanh_zero(
    float* __restrict__ P, bf16* __restrict__ Yh)
{
    int n = blockIdx.x * 256 + threadIdx.x;
    if (n >= N_NODES) return;
    float4* pr = reinterpret_cast<float4*>(P + (size_t)n * HID_F);
    union { bf16 h[HID_F]; uint4 q[2]; } yo;
    #pragma unroll
    for (int q = 0; q < HID_F / 4; ++q) {
        float4 t = pr[q];
        yo.h[4*q+0] = __float2bfloat16(tanhf(t.x));
        yo.h[4*q+1] = __float2bfloat16(tanhf(t.y));
        yo.h[4*q+2] = __float2bfloat16(tanhf(t.z));
        yo.h[4*q+3] = __float2bfloat16(tanhf(t.w));
        pr[q] = make_float4(0.f, 0.f, 0.f, 0.f);
    }
    uint4* yq = reinterpret_cast<uint4*>(Yh + (size_t)n * HID_F);
    yq[0] = yo.q[0]; yq[1] = yo.q[1];
}

// -------- Output: out = P(agg)@W2_rel + b2 + h2@W2_root -----------------------
__global__ __launch_bounds__(256) void k7_out(
    const float* __restrict__ P, const bf16* __restrict__ Yh,
    const float* __restrict__ Wrel, const float* __restrict__ b,
    const float* __restrict__ Wroot, float* __restrict__ out)
{
    __shared__ float sWrel[HID_F * OUT_F];
    __shared__ float sWroot[HID_F * OUT_F];
    __shared__ float sb[OUT_F];
    for (int i = threadIdx.x; i < HID_F * OUT_F; i += 256) {
        sWrel[i]  = Wrel[i];
        sWroot[i] = Wroot[i];
    }
    if (threadIdx.x < OUT_F) sb[threadIdx.x] = b[threadIdx.x];
    __syncthreads();

    int n = blockIdx.x * 256 + threadIdx.x;
    if (n >= N_NODES) return;

    float agg[HID_F], h[HID_F];
    const float4* pr = reinterpret_cast<const float4*>(P + (size_t)n * HID_F);
    #pragma unroll
    for (int q = 0; q < HID_F / 4; ++q) {
        float4 a = pr[q];
        agg[4*q+0] = a.x; agg[4*q+1] = a.y; agg[4*q+2] = a.z; agg[4*q+3] = a.w;
    }
    union { bf16 hh[HID_F]; uint4 q[2]; } yi;
    const uint4* yq = reinterpret_cast<const uint4*>(Yh + (size_t)n * HID_F);
    yi.q[0] = yq[0]; yi.q[1] = yq[1];
    #pragma unroll
    for (int f = 0; f < HID_F; ++f) h[f] = __bfloat162float(yi.hh[f]);

    float acc[OUT_F];
    #pragma unroll
    for (int j = 0; j < OUT_F; ++j) acc[j] = sb[j];

    #pragma unroll 2
    for (int f = 0; f < HID_F; ++f) {
        float a = agg[f], hh = h[f];
        #pragma unroll
        for (int j = 0; j < OUT_F; ++j) {
            acc[j] = fmaf(a,  sWrel[f*OUT_F + j], acc[j]);
            acc[j] = fmaf(hh, sWroot[f*OUT_F + j], acc[j]);
        }
    }

    float4* orow = reinterpret_cast<float4*>(out + (size_t)n * OUT_F);
    #pragma unroll
    for (int q = 0; q < OUT_F / 4; ++q)
        orow[q] = make_float4(acc[4*q], acc[4*q+1], acc[4*q+2], acc[4*q+3]);
}

extern "C" void kernel_launch(void* const* d_in, const int* in_sizes, int n_in,
                              void* d_out, int out_size, void* d_ws, size_t ws_size,
                              hipStream_t stream)
{
    const float* x        = (const float*)d_in[0];
    const int*   ei       = (const int*)d_in[1];
    const float* W1_rel   = (const float*)d_in[2];
    const float* b1       = (const float*)d_in[3];
    const float* W1_root  = (const float*)d_in[4];
    const float* W1b_rel  = (const float*)d_in[5];
    const float* b1b      = (const float*)d_in[6];
    const float* W1b_root = (const float*)d_in[7];
    const float* W2_rel   = (const float*)d_in[8];
    const float* b2       = (const float*)d_in[9];
    const float* W2_root  = (const float*)d_in[10];
    float* out = (float*)d_out;

    const int* src = ei;            // edge_index[0]
    const int* dst = ei + N_EDGES;  // edge_index[1]

    // Workspace (~9.6 MB). pk aliases d_out (consumed by gathers, then k7 overwrites).
    bf16* Yh    = (bf16*)d_ws;                          // [N,16] bf16 (3.2 MB)
    float* P    = (float*)(Yh + (size_t)N_NODES * HID_F); // [N,16] f32 (6.4 MB)
    int* bcnt   = (int*)(P + (size_t)N_NODES * HID_F);  // [NBKT]
    int* base   = bcnt + NBKT;                          // [NBKT+1]
    int* cursor = base + NBKT + 1;                      // [NBKT]
    unsigned int* pk = (unsigned int*)d_out;            // [E] scratch

    const int nb_n = (N_NODES + 255) / 256;

    // ---- Build: bucket counting sort (reused by all 3 layers) ----
    k_zero_b<<<1, 1024, 0, stream>>>(bcnt);
    k_bhist<<<NB_E2, 256, 0, stream>>>(dst, bcnt);
    k_bscan<<<1, 1024, 0, stream>>>(bcnt, base, cursor);
    k_partition<<<NB_E2, 256, 0, stream>>>(src, dst, cursor, pk);

    // ---- Layer 1 ----
    k1_lin48<<<nb_n, 256, 0, stream>>>(x, W1_rel, b1, W1_root, Yh, P);
    k_gather<<<NBKT, 256, 0, stream>>>(base, pk, Yh, P);
    // ---- Layer 2 ----
    k3_lin16<<<nb_n, 256, 0, stream>>>(Yh, P, W1b_rel, b1b, W1b_root);
    k_gather<<<NBKT, 256, 0, stream>>>(base, pk, Yh, P);
    // ---- Layer 3 ----
    k5_tanh_zero<<<nb_n, 256, 0, stream>>>(P, Yh);
    k_gather<<<NBKT, 256, 0, stream>>>(base, pk, Yh, P);
    k7_out<<<nb_n, 256, 0, stream>>>(P, Yh, W2_rel, b2, W2_root, out);
}

// Round 5
// 239.898 us; speedup vs baseline: 2.6947x; 2.6947x over previous
//
#include <hip/hip_runtime.h>
#include <cmath>

#define N_NODES 100000
#define N_EDGES 1600000
#define IN_F 48
#define HID_F 16
#define OUT_F 60

#define BKT 128                                  // nodes per bucket
#define NBKT ((N_NODES + BKT - 1) / BKT)         // 782
#define EPB 2048                                 // edges per block (hist/partition)
#define NB_E2 ((N_EDGES + EPB - 1) / EPB)        // 782

// ---------------- Build: two-level counting sort -> per-node CSR --------------
__global__ __launch_bounds__(1024) void k_zero_b(int* __restrict__ bcnt)
{
    if (threadIdx.x < NBKT) bcnt[threadIdx.x] = 0;
}

__global__ __launch_bounds__(256) void k_bhist(
    const int* __restrict__ dst, int* __restrict__ bcnt)
{
    __shared__ int h[NBKT];
    for (int i = threadIdx.x; i < NBKT; i += 256) h[i] = 0;
    __syncthreads();
    int base = blockIdx.x * EPB;
    #pragma unroll
    for (int i = 0; i < EPB / 256; ++i) {
        int e = base + i * 256 + threadIdx.x;
        if (e < N_EDGES) atomicAdd(&h[dst[e] >> 7], 1);
    }
    __syncthreads();
    for (int i = threadIdx.x; i < NBKT; i += 256)
        if (h[i]) atomicAdd(&bcnt[i], h[i]);
}

// Exclusive scan of 782 bucket counts -> base[NBKT+1], cursor[NBKT].
__global__ __launch_bounds__(1024) void k_bscan(
    const int* __restrict__ bcnt, int* __restrict__ base, int* __restrict__ cursor)
{
    __shared__ int tmp[1024];
    int v = (threadIdx.x < NBKT) ? bcnt[threadIdx.x] : 0;
    tmp[threadIdx.x] = v;
    __syncthreads();
    #pragma unroll
    for (int ofs = 1; ofs < 1024; ofs <<= 1) {
        int a = (threadIdx.x >= ofs) ? tmp[threadIdx.x - ofs] : 0;
        __syncthreads();
        tmp[threadIdx.x] += a;
        __syncthreads();
    }
    if (threadIdx.x < NBKT) {
        int ex = tmp[threadIdx.x] - v;
        base[threadIdx.x] = ex;
        cursor[threadIdx.x] = ex;
    }
    if (threadIdx.x == 0) base[NBKT] = N_EDGES;
}

// Partition edges into dst-buckets; packed word = (src << 7) | (dst & 127).
__global__ __launch_bounds__(256) void k_partition(
    const int* __restrict__ src, const int* __restrict__ dst,
    int* __restrict__ cursor, unsigned int* __restrict__ pk)
{
    __shared__ int cnt[NBKT];
    __shared__ int bb[NBKT];
    for (int i = threadIdx.x; i < NBKT; i += 256) cnt[i] = 0;
    __syncthreads();
    int e0 = blockIdx.x * EPB;
    int dloc[EPB / 256];
    #pragma unroll
    for (int i = 0; i < EPB / 256; ++i) {
        int e = e0 + i * 256 + threadIdx.x;
        dloc[i] = (e < N_EDGES) ? dst[e] : -1;
        if (dloc[i] >= 0) atomicAdd(&cnt[dloc[i] >> 7], 1);
    }
    __syncthreads();
    for (int i = threadIdx.x; i < NBKT; i += 256) {
        int c = cnt[i];
        bb[i] = c ? atomicAdd(&cursor[i], c) : 0;
        cnt[i] = 0;
    }
    __syncthreads();
    #pragma unroll
    for (int i = 0; i < EPB / 256; ++i) {
        int e = e0 + i * 256 + threadIdx.x;
        int d = dloc[i];
        if (d >= 0) {
            int b = d >> 7;
            int r = atomicAdd(&cnt[b], 1);
            pk[bb[b] + r] = ((unsigned int)src[e] << 7) | (unsigned int)(d & 127);
        }
    }
}

// One block per 128-node bucket: per-node CSR via LDS hist + scan + cursors.
// csr writes land in an 8KB hot window -> coalesced write-back.
__global__ __launch_bounds__(256) void k_bucket_csr(
    const int* __restrict__ base, const unsigned int* __restrict__ pk,
    int* __restrict__ off_end, int* __restrict__ csr)
{
    __shared__ int hist[BKT];
    __shared__ int tmp[BKT];
    __shared__ int cur[BKT];
    int b = blockIdx.x;
    int e0 = base[b], e1 = base[b + 1];
    if (threadIdx.x < BKT) hist[threadIdx.x] = 0;
    __syncthreads();
    for (int e = e0 + threadIdx.x; e < e1; e += 256)
        atomicAdd(&hist[pk[e] & 127u], 1);
    __syncthreads();
    int v = 0;
    if (threadIdx.x < BKT) { v = hist[threadIdx.x]; tmp[threadIdx.x] = v; }
    __syncthreads();
    #pragma unroll
    for (int ofs = 1; ofs < BKT; ofs <<= 1) {
        int a = (threadIdx.x < BKT && threadIdx.x >= ofs) ? tmp[threadIdx.x - ofs] : 0;
        __syncthreads();
        if (threadIdx.x < BKT) tmp[threadIdx.x] += a;
        __syncthreads();
    }
    if (threadIdx.x < BKT) {
        int incl = tmp[threadIdx.x];
        cur[threadIdx.x] = e0 + incl - v;            // segment start
        int n = b * BKT + threadIdx.x;
        if (n < N_NODES) off_end[n] = e0 + incl;     // segment end
    }
    __syncthreads();
    for (int e = e0 + threadIdx.x; e < e1; e += 256) {
        unsigned int p = pk[e];
        int pos = atomicAdd(&cur[p & 127u], 1);
        csr[pos] = (int)(p >> 7);
    }
}

// ---------------- Gather: P[n] += sum_{e in in(n)} Y[src[e]] ------------------
// 16 lanes per node; lane = feature index. 4-way unrolled load chains.
__global__ __launch_bounds__(256) void k_gather(
    const int* __restrict__ off_end, const int* __restrict__ csr_src,
    const float* __restrict__ Y, float* __restrict__ P)
{
    int t = blockIdx.x * 256 + threadIdx.x;
    int n = t >> 4;
    int lane = t & 15;
    if (n >= N_NODES) return;
    int e0 = (n == 0) ? 0 : off_end[n - 1];
    int e1 = off_end[n];

    float acc0 = 0.f, acc1 = 0.f, acc2 = 0.f, acc3 = 0.f;
    int e = e0;
    for (; e + 3 < e1; e += 4) {
        int s0 = csr_src[e];
        int s1 = csr_src[e + 1];
        int s2 = csr_src[e + 2];
        int s3 = csr_src[e + 3];
        acc0 += Y[(size_t)s0 * HID_F + lane];
        acc1 += Y[(size_t)s1 * HID_F + lane];
        acc2 += Y[(size_t)s2 * HID_F + lane];
        acc3 += Y[(size_t)s3 * HID_F + lane];
    }
    for (; e < e1; ++e) acc0 += Y[(size_t)csr_src[e] * HID_F + lane];
    P[(size_t)n * HID_F + lane] += (acc0 + acc1) + (acc2 + acc3);
}

// ---------------- Layer-1 node transform: Y = x@W1_rel, P = x@W1_root + b1 ----
__global__ __launch_bounds__(256) void k1_lin48(
    const float* __restrict__ x, const float* __restrict__ Wrel,
    const float* __restrict__ b, const float* __restrict__ Wroot,
    float* __restrict__ Y, float* __restrict__ P)
{
    __shared__ float sWrel[IN_F * HID_F];
    __shared__ float sWroot[IN_F * HID_F];
    __shared__ float sb[HID_F];
    for (int i = threadIdx.x; i < IN_F * HID_F; i += 256) {
        sWrel[i]  = Wrel[i];
        sWroot[i] = Wroot[i];
    }
    if (threadIdx.x < HID_F) sb[threadIdx.x] = b[threadIdx.x];
    __syncthreads();

    int n = blockIdx.x * 256 + threadIdx.x;
    if (n >= N_NODES) return;

    float xv[IN_F];
    const float4* xr = reinterpret_cast<const float4*>(x + (size_t)n * IN_F);
    #pragma unroll
    for (int i = 0; i < IN_F / 4; ++i) {
        float4 t = xr[i];
        xv[4*i+0] = t.x; xv[4*i+1] = t.y; xv[4*i+2] = t.z; xv[4*i+3] = t.w;
    }

    float accR[HID_F], accT[HID_F];
    #pragma unroll
    for (int f = 0; f < HID_F; ++f) { accR[f] = 0.0f; accT[f] = sb[f]; }

    #pragma unroll 6
    for (int k = 0; k < IN_F; ++k) {
        float xk = xv[k];
        #pragma unroll
        for (int f = 0; f < HID_F; ++f) {
            accR[f] = fmaf(xk, sWrel[k*HID_F + f], accR[f]);
            accT[f] = fmaf(xk, sWroot[k*HID_F + f], accT[f]);
        }
    }

    float4* yr = reinterpret_cast<float4*>(Y + (size_t)n * HID_F);
    float4* pr = reinterpret_cast<float4*>(P + (size_t)n * HID_F);
    #pragma unroll
    for (int q = 0; q < HID_F / 4; ++q) {
        yr[q] = make_float4(accR[4*q], accR[4*q+1], accR[4*q+2], accR[4*q+3]);
        pr[q] = make_float4(accT[4*q], accT[4*q+1], accT[4*q+2], accT[4*q+3]);
    }
}

// -------- Layer-2 node transform (in place): h=tanh(P); Y=h@Wrel; P=h@Wroot+b --
__global__ __launch_bounds__(256) void k3_lin16(
    float* __restrict__ Y, float* __restrict__ P,
    const float* __restrict__ Wrel, const float* __restrict__ b,
    const float* __restrict__ Wroot)
{
    __shared__ float sWrel[HID_F * HID_F];
    __shared__ float sWroot[HID_F * HID_F];
    __shared__ float sb[HID_F];
    if (threadIdx.x < HID_F * HID_F) {
        sWrel[threadIdx.x]  = Wrel[threadIdx.x];
        sWroot[threadIdx.x] = Wroot[threadIdx.x];
    }
    if (threadIdx.x < HID_F) sb[threadIdx.x] = b[threadIdx.x];
    __syncthreads();

    int n = blockIdx.x * 256 + threadIdx.x;
    if (n >= N_NODES) return;

    float h[HID_F];
    float4* pr = reinterpret_cast<float4*>(P + (size_t)n * HID_F);
    #pragma unroll
    for (int q = 0; q < HID_F / 4; ++q) {
        float4 t = pr[q];
        h[4*q+0] = tanhf(t.x); h[4*q+1] = tanhf(t.y);
        h[4*q+2] = tanhf(t.z); h[4*q+3] = tanhf(t.w);
    }

    float accR[HID_F], accT[HID_F];
    #pragma unroll
    for (int f = 0; f < HID_F; ++f) { accR[f] = 0.0f; accT[f] = sb[f]; }

    #pragma unroll
    for (int k = 0; k < HID_F; ++k) {
        float hk = h[k];
        #pragma unroll
        for (int f = 0; f < HID_F; ++f) {
            accR[f] = fmaf(hk, sWrel[k*HID_F + f], accR[f]);
            accT[f] = fmaf(hk, sWroot[k*HID_F + f], accT[f]);
        }
    }

    float4* yr = reinterpret_cast<float4*>(Y + (size_t)n * HID_F);
    #pragma unroll
    for (int q = 0; q < HID_F / 4; ++q) {
        yr[q] = make_float4(accR[4*q], accR[4*q+1], accR[4*q+2], accR[4*q+3]);
        pr[q] = make_float4(accT[4*q], accT[4*q+1], accT[4*q+2], accT[4*q+3]);
    }
}

// -------- Layer-3 prep: Y = tanh(P) (=h2), P = 0 (agg accumulator) ------------
__global__ __launch_bounds__(256) void k5_tanh_zero(
    float* __restrict__ P, float* __restrict__ Y)
{
    int n = blockIdx.x * 256 + threadIdx.x;
    if (n >= N_NODES) return;
    float4* pr = reinterpret_cast<float4*>(P + (size_t)n * HID_F);
    float4* yr = reinterpret_cast<float4*>(Y + (size_t)n * HID_F);
    #pragma unroll
    for (int q = 0; q < HID_F / 4; ++q) {
        float4 t = pr[q];
        yr[q] = make_float4(tanhf(t.x), tanhf(t.y), tanhf(t.z), tanhf(t.w));
        pr[q] = make_float4(0.f, 0.f, 0.f, 0.f);
    }
}

// -------- Output: out = P(agg)@W2_rel + b2 + Y(h2)@W2_root --------------------
__global__ __launch_bounds__(256) void k7_out(
    const float* __restrict__ P, const float* __restrict__ Y,
    const float* __restrict__ Wrel, const float* __restrict__ b,
    const float* __restrict__ Wroot, float* __restrict__ out)
{
    __shared__ float sWrel[HID_F * OUT_F];
    __shared__ float sWroot[HID_F * OUT_F];
    __shared__ float sb[OUT_F];
    for (int i = threadIdx.x; i < HID_F * OUT_F; i += 256) {
        sWrel[i]  = Wrel[i];
        sWroot[i] = Wroot[i];
    }
    if (threadIdx.x < OUT_F) sb[threadIdx.x] = b[threadIdx.x];
    __syncthreads();

    int n = blockIdx.x * 256 + threadIdx.x;
    if (n >= N_NODES) return;

    float agg[HID_F], h[HID_F];
    const float4* pr = reinterpret_cast<const float4*>(P + (size_t)n * HID_F);
    const float4* yr = reinterpret_cast<const float4*>(Y + (size_t)n * HID_F);
    #pragma unroll
    for (int q = 0; q < HID_F / 4; ++q) {
        float4 a = pr[q], hh = yr[q];
        agg[4*q+0] = a.x; agg[4*q+1] = a.y; agg[4*q+2] = a.z; agg[4*q+3] = a.w;
        h[4*q+0] = hh.x;  h[4*q+1] = hh.y;  h[4*q+2] = hh.z;  h[4*q+3] = hh.w;
    }

    float acc[OUT_F];
    #pragma unroll
    for (int j = 0; j < OUT_F; ++j) acc[j] = sb[j];

    #pragma unroll 2
    for (int f = 0; f < HID_F; ++f) {
        float a = agg[f], hh = h[f];
        #pragma unroll
        for (int j = 0; j < OUT_F; ++j) {
            acc[j] = fmaf(a,  sWrel[f*OUT_F + j], acc[j]);
            acc[j] = fmaf(hh, sWroot[f*OUT_F + j], acc[j]);
        }
    }

    float4* orow = reinterpret_cast<float4*>(out + (size_t)n * OUT_F);
    #pragma unroll
    for (int q = 0; q < OUT_F / 4; ++q)
        orow[q] = make_float4(acc[4*q], acc[4*q+1], acc[4*q+2], acc[4*q+3]);
}

extern "C" void kernel_launch(void* const* d_in, const int* in_sizes, int n_in,
                              void* d_out, int out_size, void* d_ws, size_t ws_size,
                              hipStream_t stream)
{
    const float* x        = (const float*)d_in[0];
    const int*   ei       = (const int*)d_in[1];
    const float* W1_rel   = (const float*)d_in[2];
    const float* b1       = (const float*)d_in[3];
    const float* W1_root  = (const float*)d_in[4];
    const float* W1b_rel  = (const float*)d_in[5];
    const float* b1b      = (const float*)d_in[6];
    const float* W1b_root = (const float*)d_in[7];
    const float* W2_rel   = (const float*)d_in[8];
    const float* b2       = (const float*)d_in[9];
    const float* W2_root  = (const float*)d_in[10];
    float* out = (float*)d_out;

    const int* src = ei;            // edge_index[0]
    const int* dst = ei + N_EDGES;  // edge_index[1]

    // Workspace (~19.6 MB). pk aliases d_out (consumed in build, then k7 overwrites).
    float* Y     = (float*)d_ws;                          // [N,16]
    float* P     = Y + (size_t)N_NODES * HID_F;           // [N,16]
    int* csr     = (int*)(P + (size_t)N_NODES * HID_F);   // [E]
    int* off_end = csr + N_EDGES;                         // [N]
    int* bcnt    = off_end + N_NODES;                     // [NBKT]
    int* base    = bcnt + NBKT;                           // [NBKT+1]
    int* cursor  = base + NBKT + 1;                       // [NBKT]
    unsigned int* pk = (unsigned int*)d_out;              // [E] scratch

    const int nb_n = (N_NODES + 255) / 256;
    const int nb_g = (N_NODES * HID_F + 255) / 256;

    // ---- Build: bucket counting sort -> per-node CSR (reused by 3 layers) ----
    k_zero_b<<<1, 1024, 0, stream>>>(bcnt);
    k_bhist<<<NB_E2, 256, 0, stream>>>(dst, bcnt);
    k_bscan<<<1, 1024, 0, stream>>>(bcnt, base, cursor);
    k_partition<<<NB_E2, 256, 0, stream>>>(src, dst, cursor, pk);
    k_bucket_csr<<<NBKT, 256, 0, stream>>>(base, pk, off_end, csr);

    // ---- Layer 1 ----
    k1_lin48<<<nb_n, 256, 0, stream>>>(x, W1_rel, b1, W1_root, Y, P);
    k_gather<<<nb_g, 256, 0, stream>>>(off_end, csr, Y, P);
    // ---- Layer 2 ----
    k3_lin16<<<nb_n, 256, 0, stream>>>(Y, P, W1b_rel, b1b, W1b_root);
    k_gather<<<nb_g, 256, 0, stream>>>(off_end, csr, Y, P);
    // ---- Layer 3 ----
    k5_tanh_zero<<<nb_n, 256, 0, stream>>>(P, Y);
    k_gather<<<nb_g, 256, 0, stream>>>(off_end, csr, Y, P);
    k7_out<<<nb_n, 256, 0, stream>>>(P, Y, W2_rel, b2, W2_root, out);
}

// Round 6
// 209.682 us; speedup vs baseline: 3.0831x; 1.1441x over previous
//
#include <hip/hip_runtime.h>
#include <cmath>

#define N_NODES 100000
#define N_EDGES 1600000
#define IN_F 48
#define HID_F 16
#define OUT_F 60

#define BKT 256                                  // nodes per bucket
#define NBKT ((N_NODES + BKT - 1) / BKT)         // 391
#define EPB 8192                                 // edges per partition block
#define NB_P ((N_EDGES + EPB - 1) / EPB)         // 196
#define EPB_H 2048                               // edges per hist block
#define NB_H ((N_EDGES + EPB_H - 1) / EPB_H)     // 782

// ---------------- Build: two-level counting sort -> per-node CSR --------------
__global__ __launch_bounds__(1024) void k_zero_b(int* __restrict__ bcnt)
{
    if (threadIdx.x < NBKT) bcnt[threadIdx.x] = 0;
}

__global__ __launch_bounds__(256) void k_bhist(
    const int* __restrict__ dst, int* __restrict__ bcnt)
{
    __shared__ int h[NBKT];
    for (int i = threadIdx.x; i < NBKT; i += 256) h[i] = 0;
    __syncthreads();
    int base = blockIdx.x * EPB_H;
    #pragma unroll
    for (int i = 0; i < EPB_H / 256; ++i) {
        int e = base + i * 256 + threadIdx.x;
        if (e < N_EDGES) atomicAdd(&h[dst[e] >> 8], 1);
    }
    __syncthreads();
    for (int i = threadIdx.x; i < NBKT; i += 256)
        if (h[i]) atomicAdd(&bcnt[i], h[i]);
}

// Exclusive scan of 391 bucket counts -> base[NBKT+1], cursor[NBKT].
__global__ __launch_bounds__(1024) void k_bscan(
    const int* __restrict__ bcnt, int* __restrict__ base, int* __restrict__ cursor)
{
    __shared__ int tmp[1024];
    int v = (threadIdx.x < NBKT) ? bcnt[threadIdx.x] : 0;
    tmp[threadIdx.x] = v;
    __syncthreads();
    #pragma unroll
    for (int ofs = 1; ofs < 1024; ofs <<= 1) {
        int a = (threadIdx.x >= ofs) ? tmp[threadIdx.x - ofs] : 0;
        __syncthreads();
        tmp[threadIdx.x] += a;
        __syncthreads();
    }
    if (threadIdx.x < NBKT) {
        int ex = tmp[threadIdx.x] - v;
        base[threadIdx.x] = ex;
        cursor[threadIdx.x] = ex;
    }
    if (threadIdx.x == 0) base[NBKT] = N_EDGES;
}

// Partition edges into dst-buckets; packed word = (src << 8) | (dst & 255).
// 1024 threads/block, EPB=8192: run length EPB/NBKT ~= 21 words -> coalescible
// writes (~10 MB total), 16 waves/block for latency hiding.
__global__ __launch_bounds__(1024) void k_partition(
    const int* __restrict__ src, const int* __restrict__ dst,
    int* __restrict__ cursor, unsigned int* __restrict__ pk)
{
    __shared__ int cnt[NBKT];
    __shared__ int bb[NBKT];
    for (int i = threadIdx.x; i < NBKT; i += 1024) cnt[i] = 0;
    __syncthreads();
    int e0 = blockIdx.x * EPB;
    int dloc[EPB / 1024];
    #pragma unroll
    for (int i = 0; i < EPB / 1024; ++i) {
        int e = e0 + i * 1024 + threadIdx.x;
        dloc[i] = (e < N_EDGES) ? dst[e] : -1;
        if (dloc[i] >= 0) atomicAdd(&cnt[dloc[i] >> 8], 1);
    }
    __syncthreads();
    for (int i = threadIdx.x; i < NBKT; i += 1024) {
        int c = cnt[i];
        bb[i] = c ? atomicAdd(&cursor[i], c) : 0;
        cnt[i] = 0;
    }
    __syncthreads();
    #pragma unroll
    for (int i = 0; i < EPB / 1024; ++i) {
        int e = e0 + i * 1024 + threadIdx.x;
        int d = dloc[i];
        if (d >= 0) {
            int b = d >> 8;
            int r = atomicAdd(&cnt[b], 1);
            pk[bb[b] + r] = ((unsigned int)src[e] << 8) | (unsigned int)(d & 255);
        }
    }
}

// One block per 256-node bucket (1024 threads, 16 waves): per-node CSR via
// LDS hist + scan + bump cursors; csr writes land in a 16KB hot window.
__global__ __launch_bounds__(1024) void k_bucket_csr(
    const int* __restrict__ base, const unsigned int* __restrict__ pk,
    int* __restrict__ off_end, int* __restrict__ csr)
{
    __shared__ int hist[BKT];
    __shared__ int tmp[BKT];
    __shared__ int cur[BKT];
    int b = blockIdx.x;
    int e0 = base[b], e1 = base[b + 1];
    if (threadIdx.x < BKT) hist[threadIdx.x] = 0;
    __syncthreads();
    for (int e = e0 + threadIdx.x; e < e1; e += 1024)
        atomicAdd(&hist[pk[e] & 255u], 1);
    __syncthreads();
    int v = 0;
    if (threadIdx.x < BKT) { v = hist[threadIdx.x]; tmp[threadIdx.x] = v; }
    __syncthreads();
    #pragma unroll
    for (int ofs = 1; ofs < BKT; ofs <<= 1) {
        int a = (threadIdx.x < BKT && threadIdx.x >= ofs) ? tmp[threadIdx.x - ofs] : 0;
        __syncthreads();
        if (threadIdx.x < BKT) tmp[threadIdx.x] += a;
        __syncthreads();
    }
    if (threadIdx.x < BKT) {
        int incl = tmp[threadIdx.x];
        cur[threadIdx.x] = e0 + incl - v;            // segment start
        int n = b * BKT + threadIdx.x;
        if (n < N_NODES) off_end[n] = e0 + incl;     // segment end
    }
    __syncthreads();
    for (int e = e0 + threadIdx.x; e < e1; e += 1024) {
        unsigned int p = pk[e];
        int pos = atomicAdd(&cur[p & 255u], 1);
        csr[pos] = (int)(p >> 8);
    }
}

// ---------------- Gather: P[n] += sum_{e in in(n)} Y[src[e]] ------------------
// 16 lanes per node; lane = feature index. 4-way unrolled load chains.
__global__ __launch_bounds__(256) void k_gather(
    const int* __restrict__ off_end, const int* __restrict__ csr_src,
    const float* __restrict__ Y, float* __restrict__ P)
{
    int t = blockIdx.x * 256 + threadIdx.x;
    int n = t >> 4;
    int lane = t & 15;
    if (n >= N_NODES) return;
    int e0 = (n == 0) ? 0 : off_end[n - 1];
    int e1 = off_end[n];

    float acc0 = 0.f, acc1 = 0.f, acc2 = 0.f, acc3 = 0.f;
    int e = e0;
    for (; e + 3 < e1; e += 4) {
        int s0 = csr_src[e];
        int s1 = csr_src[e + 1];
        int s2 = csr_src[e + 2];
        int s3 = csr_src[e + 3];
        acc0 += Y[(size_t)s0 * HID_F + lane];
        acc1 += Y[(size_t)s1 * HID_F + lane];
        acc2 += Y[(size_t)s2 * HID_F + lane];
        acc3 += Y[(size_t)s3 * HID_F + lane];
    }
    for (; e < e1; ++e) acc0 += Y[(size_t)csr_src[e] * HID_F + lane];
    P[(size_t)n * HID_F + lane] += (acc0 + acc1) + (acc2 + acc3);
}

// ---------------- Layer-1 node transform: Y = x@W1_rel, P = x@W1_root + b1 ----
__global__ __launch_bounds__(256) void k1_lin48(
    const float* __restrict__ x, const float* __restrict__ Wrel,
    const float* __restrict__ b, const float* __restrict__ Wroot,
    float* __restrict__ Y, float* __restrict__ P)
{
    __shared__ float sWrel[IN_F * HID_F];
    __shared__ float sWroot[IN_F * HID_F];
    __shared__ float sb[HID_F];
    for (int i = threadIdx.x; i < IN_F * HID_F; i += 256) {
        sWrel[i]  = Wrel[i];
        sWroot[i] = Wroot[i];
    }
    if (threadIdx.x < HID_F) sb[threadIdx.x] = b[threadIdx.x];
    __syncthreads();

    int n = blockIdx.x * 256 + threadIdx.x;
    if (n >= N_NODES) return;

    float xv[IN_F];
    const float4* xr = reinterpret_cast<const float4*>(x + (size_t)n * IN_F);
    #pragma unroll
    for (int i = 0; i < IN_F / 4; ++i) {
        float4 t = xr[i];
        xv[4*i+0] = t.x; xv[4*i+1] = t.y; xv[4*i+2] = t.z; xv[4*i+3] = t.w;
    }

    float accR[HID_F], accT[HID_F];
    #pragma unroll
    for (int f = 0; f < HID_F; ++f) { accR[f] = 0.0f; accT[f] = sb[f]; }

    #pragma unroll 6
    for (int k = 0; k < IN_F; ++k) {
        float xk = xv[k];
        #pragma unroll
        for (int f = 0; f < HID_F; ++f) {
            accR[f] = fmaf(xk, sWrel[k*HID_F + f], accR[f]);
            accT[f] = fmaf(xk, sWroot[k*HID_F + f], accT[f]);
        }
    }

    float4* yr = reinterpret_cast<float4*>(Y + (size_t)n * HID_F);
    float4* pr = reinterpret_cast<float4*>(P + (size_t)n * HID_F);
    #pragma unroll
    for (int q = 0; q < HID_F / 4; ++q) {
        yr[q] = make_float4(accR[4*q], accR[4*q+1], accR[4*q+2], accR[4*q+3]);
        pr[q] = make_float4(accT[4*q], accT[4*q+1], accT[4*q+2], accT[4*q+3]);
    }
}

// -------- Layer-2 node transform (in place): h=tanh(P); Y=h@Wrel; P=h@Wroot+b --
__global__ __launch_bounds__(256) void k3_lin16(
    float* __restrict__ Y, float* __restrict__ P,
    const float* __restrict__ Wrel, const float* __restrict__ b,
    const float* __restrict__ Wroot)
{
    __shared__ float sWrel[HID_F * HID_F];
    __shared__ float sWroot[HID_F * HID_F];
    __shared__ float sb[HID_F];
    if (threadIdx.x < HID_F * HID_F) {
        sWrel[threadIdx.x]  = Wrel[threadIdx.x];
        sWroot[threadIdx.x] = Wroot[threadIdx.x];
    }
    if (threadIdx.x < HID_F) sb[threadIdx.x] = b[threadIdx.x];
    __syncthreads();

    int n = blockIdx.x * 256 + threadIdx.x;
    if (n >= N_NODES) return;

    float h[HID_F];
    float4* pr = reinterpret_cast<float4*>(P + (size_t)n * HID_F);
    #pragma unroll
    for (int q = 0; q < HID_F / 4; ++q) {
        float4 t = pr[q];
        h[4*q+0] = tanhf(t.x); h[4*q+1] = tanhf(t.y);
        h[4*q+2] = tanhf(t.z); h[4*q+3] = tanhf(t.w);
    }

    float accR[HID_F], accT[HID_F];
    #pragma unroll
    for (int f = 0; f < HID_F; ++f) { accR[f] = 0.0f; accT[f] = sb[f]; }

    #pragma unroll
    for (int k = 0; k < HID_F; ++k) {
        float hk = h[k];
        #pragma unroll
        for (int f = 0; f < HID_F; ++f) {
            accR[f] = fmaf(hk, sWrel[k*HID_F + f], accR[f]);
            accT[f] = fmaf(hk, sWroot[k*HID_F + f], accT[f]);
        }
    }

    float4* yr = reinterpret_cast<float4*>(Y + (size_t)n * HID_F);
    #pragma unroll
    for (int q = 0; q < HID_F / 4; ++q) {
        yr[q] = make_float4(accR[4*q], accR[4*q+1], accR[4*q+2], accR[4*q+3]);
        pr[q] = make_float4(accT[4*q], accT[4*q+1], accT[4*q+2], accT[4*q+3]);
    }
}

// -------- Layer-3 prep: Y = tanh(P) (=h2), P = 0 (agg accumulator) ------------
__global__ __launch_bounds__(256) void k5_tanh_zero(
    float* __restrict__ P, float* __restrict__ Y)
{
    int n = blockIdx.x * 256 + threadIdx.x;
    if (n >= N_NODES) return;
    float4* pr = reinterpret_cast<float4*>(P + (size_t)n * HID_F);
    float4* yr = reinterpret_cast<float4*>(Y + (size_t)n * HID_F);
    #pragma unroll
    for (int q = 0; q < HID_F / 4; ++q) {
        float4 t = pr[q];
        yr[q] = make_float4(tanhf(t.x), tanhf(t.y), tanhf(t.z), tanhf(t.w));
        pr[q] = make_float4(0.f, 0.f, 0.f, 0.f);
    }
}

// -------- Output: out = P(agg)@W2_rel + b2 + Y(h2)@W2_root --------------------
__global__ __launch_bounds__(256) void k7_out(
    const float* __restrict__ P, const float* __restrict__ Y,
    const float* __restrict__ Wrel, const float* __restrict__ b,
    const float* __restrict__ Wroot, float* __restrict__ out)
{
    __shared__ float sWrel[HID_F * OUT_F];
    __shared__ float sWroot[HID_F * OUT_F];
    __shared__ float sb[OUT_F];
    for (int i = threadIdx.x; i < HID_F * OUT_F; i += 256) {
        sWrel[i]  = Wrel[i];
        sWroot[i] = Wroot[i];
    }
    if (threadIdx.x < OUT_F) sb[threadIdx.x] = b[threadIdx.x];
    __syncthreads();

    int n = blockIdx.x * 256 + threadIdx.x;
    if (n >= N_NODES) return;

    float agg[HID_F], h[HID_F];
    const float4* pr = reinterpret_cast<const float4*>(P + (size_t)n * HID_F);
    const float4* yr = reinterpret_cast<const float4*>(Y + (size_t)n * HID_F);
    #pragma unroll
    for (int q = 0; q < HID_F / 4; ++q) {
        float4 a = pr[q], hh = yr[q];
        agg[4*q+0] = a.x; agg[4*q+1] = a.y; agg[4*q+2] = a.z; agg[4*q+3] = a.w;
        h[4*q+0] = hh.x;  h[4*q+1] = hh.y;  h[4*q+2] = hh.z;  h[4*q+3] = hh.w;
    }

    float acc[OUT_F];
    #pragma unroll
    for (int j = 0; j < OUT_F; ++j) acc[j] = sb[j];

    #pragma unroll 2
    for (int f = 0; f < HID_F; ++f) {
        float a = agg[f], hh = h[f];
        #pragma unroll
        for (int j = 0; j < OUT_F; ++j) {
            acc[j] = fmaf(a,  sWrel[f*OUT_F + j], acc[j]);
            acc[j] = fmaf(hh, sWroot[f*OUT_F + j], acc[j]);
        }
    }

    float4* orow = reinterpret_cast<float4*>(out + (size_t)n * OUT_F);
    #pragma unroll
    for (int q = 0; q < OUT_F / 4; ++q)
        orow[q] = make_float4(acc[4*q], acc[4*q+1], acc[4*q+2], acc[4*q+3]);
}

extern "C" void kernel_launch(void* const* d_in, const int* in_sizes, int n_in,
                              void* d_out, int out_size, void* d_ws, size_t ws_size,
                              hipStream_t stream)
{
    const float* x        = (const float*)d_in[0];
    const int*   ei       = (const int*)d_in[1];
    const float* W1_rel   = (const float*)d_in[2];
    const float* b1       = (const float*)d_in[3];
    const float* W1_root  = (const float*)d_in[4];
    const float* W1b_rel  = (const float*)d_in[5];
    const float* b1b      = (const float*)d_in[6];
    const float* W1b_root = (const float*)d_in[7];
    const float* W2_rel   = (const float*)d_in[8];
    const float* b2       = (const float*)d_in[9];
    const float* W2_root  = (const float*)d_in[10];
    float* out = (float*)d_out;

    const int* src = ei;            // edge_index[0]
    const int* dst = ei + N_EDGES;  // edge_index[1]

    // Workspace (~19.6 MB). pk aliases d_out (consumed in build, then k7 overwrites).
    float* Y     = (float*)d_ws;                          // [N,16]
    float* P     = Y + (size_t)N_NODES * HID_F;           // [N,16]
    int* csr     = (int*)(P + (size_t)N_NODES * HID_F);   // [E]
    int* off_end = csr + N_EDGES;                         // [N]
    int* bcnt    = off_end + N_NODES;                     // [NBKT]
    int* base    = bcnt + NBKT;                           // [NBKT+1]
    int* cursor  = base + NBKT + 1;                       // [NBKT]
    unsigned int* pk = (unsigned int*)d_out;              // [E] scratch

    const int nb_n = (N_NODES + 255) / 256;
    const int nb_g = (N_NODES * HID_F + 255) / 256;

    // ---- Build: bucket counting sort -> per-node CSR (reused by 3 layers) ----
    k_zero_b<<<1, 1024, 0, stream>>>(bcnt);
    k_bhist<<<NB_H, 256, 0, stream>>>(dst, bcnt);
    k_bscan<<<1, 1024, 0, stream>>>(bcnt, base, cursor);
    k_partition<<<NB_P, 1024, 0, stream>>>(src, dst, cursor, pk);
    k_bucket_csr<<<NBKT, 1024, 0, stream>>>(base, pk, off_end, csr);

    // ---- Layer 1 ----
    k1_lin48<<<nb_n, 256, 0, stream>>>(x, W1_rel, b1, W1_root, Y, P);
    k_gather<<<nb_g, 256, 0, stream>>>(off_end, csr, Y, P);
    // ---- Layer 2 ----
    k3_lin16<<<nb_n, 256, 0, stream>>>(Y, P, W1b_rel, b1b, W1b_root);
    k_gather<<<nb_g, 256, 0, stream>>>(off_end, csr, Y, P);
    // ---- Layer 3 ----
    k5_tanh_zero<<<nb_n, 256, 0, stream>>>(P, Y);
    k_gather<<<nb_g, 256, 0, stream>>>(off_end, csr, Y, P);
    k7_out<<<nb_n, 256, 0, stream>>>(P, Y, W2_rel, b2, W2_root, out);
}

// Round 7
// 170.465 us; speedup vs baseline: 3.7924x; 1.2301x over previous
//
#include <hip/hip_runtime.h>
#include <hip/hip_bf16.h>
#include <cmath>

#define N_NODES 100000
#define N_EDGES 1600000
#define IN_F 48
#define HID_F 16
#define OUT_F 60

#define BKT 256                                  // nodes per bucket
#define NBKT ((N_NODES + BKT - 1) / BKT)         // 391
#define EPB 8192                                 // edges per partition block
#define NB_P ((N_EDGES + EPB - 1) / EPB)         // 196
#define EPB_H 2048                               // edges per hist block
#define NB_H ((N_EDGES + EPB_H - 1) / EPB_H)     // 782

typedef __hip_bfloat16 bf16;

__device__ __forceinline__ float bf2f(unsigned short u)
{
    return __uint_as_float(((unsigned int)u) << 16);
}

// ---------------- Build: two-level counting sort -> per-node CSR --------------
__global__ __launch_bounds__(1024) void k_zero_b(int* __restrict__ bcnt)
{
    if (threadIdx.x < NBKT) bcnt[threadIdx.x] = 0;
}

__global__ __launch_bounds__(256) void k_bhist(
    const int* __restrict__ dst, int* __restrict__ bcnt)
{
    __shared__ int h[NBKT];
    for (int i = threadIdx.x; i < NBKT; i += 256) h[i] = 0;
    __syncthreads();
    int base = blockIdx.x * EPB_H;
    #pragma unroll
    for (int i = 0; i < EPB_H / 256; ++i) {
        int e = base + i * 256 + threadIdx.x;
        if (e < N_EDGES) atomicAdd(&h[dst[e] >> 8], 1);
    }
    __syncthreads();
    for (int i = threadIdx.x; i < NBKT; i += 256)
        if (h[i]) atomicAdd(&bcnt[i], h[i]);
}

__global__ __launch_bounds__(1024) void k_bscan(
    const int* __restrict__ bcnt, int* __restrict__ base, int* __restrict__ cursor)
{
    __shared__ int tmp[1024];
    int v = (threadIdx.x < NBKT) ? bcnt[threadIdx.x] : 0;
    tmp[threadIdx.x] = v;
    __syncthreads();
    #pragma unroll
    for (int ofs = 1; ofs < 1024; ofs <<= 1) {
        int a = (threadIdx.x >= ofs) ? tmp[threadIdx.x - ofs] : 0;
        __syncthreads();
        tmp[threadIdx.x] += a;
        __syncthreads();
    }
    if (threadIdx.x < NBKT) {
        int ex = tmp[threadIdx.x] - v;
        base[threadIdx.x] = ex;
        cursor[threadIdx.x] = ex;
    }
    if (threadIdx.x == 0) base[NBKT] = N_EDGES;
}

// Partition edges into dst-buckets; packed word = (src << 8) | (dst & 255).
// EPB=8192 keeps run length ~21 words (write-coalescible); 16 waves/block.
__global__ __launch_bounds__(1024) void k_partition(
    const int* __restrict__ src, const int* __restrict__ dst,
    int* __restrict__ cursor, unsigned int* __restrict__ pk)
{
    __shared__ int cnt[NBKT];
    __shared__ int bb[NBKT];
    for (int i = threadIdx.x; i < NBKT; i += 1024) cnt[i] = 0;
    __syncthreads();
    int e0 = blockIdx.x * EPB;
    int dloc[EPB / 1024];
    #pragma unroll
    for (int i = 0; i < EPB / 1024; ++i) {
        int e = e0 + i * 1024 + threadIdx.x;
        dloc[i] = (e < N_EDGES) ? dst[e] : -1;
        if (dloc[i] >= 0) atomicAdd(&cnt[dloc[i] >> 8], 1);
    }
    __syncthreads();
    for (int i = threadIdx.x; i < NBKT; i += 1024) {
        int c = cnt[i];
        bb[i] = c ? atomicAdd(&cursor[i], c) : 0;
        cnt[i] = 0;
    }
    __syncthreads();
    #pragma unroll
    for (int i = 0; i < EPB / 1024; ++i) {
        int e = e0 + i * 1024 + threadIdx.x;
        int d = dloc[i];
        if (d >= 0) {
            int b = d >> 8;
            int r = atomicAdd(&cnt[b], 1);
            pk[bb[b] + r] = ((unsigned int)src[e] << 8) | (unsigned int)(d & 255);
        }
    }
}

// One block per 256-node bucket (16 waves): per-node CSR in a 16KB hot window.
__global__ __launch_bounds__(1024) void k_bucket_csr(
    const int* __restrict__ base, const unsigned int* __restrict__ pk,
    int* __restrict__ off_end, int* __restrict__ csr)
{
    __shared__ int hist[BKT];
    __shared__ int tmp[BKT];
    __shared__ int cur[BKT];
    int b = blockIdx.x;
    int e0 = base[b], e1 = base[b + 1];
    if (threadIdx.x < BKT) hist[threadIdx.x] = 0;
    __syncthreads();
    for (int e = e0 + threadIdx.x; e < e1; e += 1024)
        atomicAdd(&hist[pk[e] & 255u], 1);
    __syncthreads();
    int v = 0;
    if (threadIdx.x < BKT) { v = hist[threadIdx.x]; tmp[threadIdx.x] = v; }
    __syncthreads();
    #pragma unroll
    for (int ofs = 1; ofs < BKT; ofs <<= 1) {
        int a = (threadIdx.x < BKT && threadIdx.x >= ofs) ? tmp[threadIdx.x - ofs] : 0;
        __syncthreads();
        if (threadIdx.x < BKT) tmp[threadIdx.x] += a;
        __syncthreads();
    }
    if (threadIdx.x < BKT) {
        int incl = tmp[threadIdx.x];
        cur[threadIdx.x] = e0 + incl - v;
        int n = b * BKT + threadIdx.x;
        if (n < N_NODES) off_end[n] = e0 + incl;
    }
    __syncthreads();
    for (int e = e0 + threadIdx.x; e < e1; e += 1024) {
        unsigned int p = pk[e];
        int pos = atomicAdd(&cur[p & 255u], 1);
        csr[pos] = (int)(p >> 8);
    }
}

// Shared gather body: 16 lanes per node, lane = feature; 4-way unrolled chains.
__device__ __forceinline__ float gather_feat(
    const int* __restrict__ off_end, const int* __restrict__ csr_src,
    const unsigned short* __restrict__ Yu, int n, int lane)
{
    int e0 = (n == 0) ? 0 : off_end[n - 1];
    int e1 = off_end[n];
    float a0 = 0.f, a1 = 0.f, a2 = 0.f, a3 = 0.f;
    int e = e0;
    for (; e + 3 < e1; e += 4) {
        int s0 = csr_src[e];
        int s1 = csr_src[e + 1];
        int s2 = csr_src[e + 2];
        int s3 = csr_src[e + 3];
        a0 += bf2f(Yu[(size_t)s0 * HID_F + lane]);
        a1 += bf2f(Yu[(size_t)s1 * HID_F + lane]);
        a2 += bf2f(Yu[(size_t)s2 * HID_F + lane]);
        a3 += bf2f(Yu[(size_t)s3 * HID_F + lane]);
    }
    for (; e < e1; ++e) a0 += bf2f(Yu[(size_t)csr_src[e] * HID_F + lane]);
    return (a0 + a1) + (a2 + a3);
}

// ---------------- Layer-1: Ya = bf16(x@W1_rel), R = x@W1_root + b1 ------------
__global__ __launch_bounds__(256) void k1_lin48(
    const float* __restrict__ x, const float* __restrict__ Wrel,
    const float* __restrict__ b, const float* __restrict__ Wroot,
    bf16* __restrict__ Ya, float* __restrict__ R)
{
    __shared__ float sWrel[IN_F * HID_F];
    __shared__ float sWroot[IN_F * HID_F];
    __shared__ float sb[HID_F];
    for (int i = threadIdx.x; i < IN_F * HID_F; i += 256) {
        sWrel[i]  = Wrel[i];
        sWroot[i] = Wroot[i];
    }
    if (threadIdx.x < HID_F) sb[threadIdx.x] = b[threadIdx.x];
    __syncthreads();

    int n = blockIdx.x * 256 + threadIdx.x;
    if (n >= N_NODES) return;

    float xv[IN_F];
    const float4* xr = reinterpret_cast<const float4*>(x + (size_t)n * IN_F);
    #pragma unroll
    for (int i = 0; i < IN_F / 4; ++i) {
        float4 t = xr[i];
        xv[4*i+0] = t.x; xv[4*i+1] = t.y; xv[4*i+2] = t.z; xv[4*i+3] = t.w;
    }

    float accR[HID_F], accT[HID_F];
    #pragma unroll
    for (int f = 0; f < HID_F; ++f) { accR[f] = 0.0f; accT[f] = sb[f]; }

    #pragma unroll 6
    for (int k = 0; k < IN_F; ++k) {
        float xk = xv[k];
        #pragma unroll
        for (int f = 0; f < HID_F; ++f) {
            accR[f] = fmaf(xk, sWrel[k*HID_F + f], accR[f]);
            accT[f] = fmaf(xk, sWroot[k*HID_F + f], accT[f]);
        }
    }

    union { bf16 h[HID_F]; uint4 q[2]; } yo;
    #pragma unroll
    for (int f = 0; f < HID_F; ++f) yo.h[f] = __float2bfloat16(accR[f]);
    uint4* yq = reinterpret_cast<uint4*>(Ya + (size_t)n * HID_F);
    yq[0] = yo.q[0]; yq[1] = yo.q[1];

    float4* rr = reinterpret_cast<float4*>(R + (size_t)n * HID_F);
    #pragma unroll
    for (int q = 0; q < HID_F / 4; ++q)
        rr[q] = make_float4(accT[4*q], accT[4*q+1], accT[4*q+2], accT[4*q+3]);
}

// -------- kA: gather(Ya) + h=tanh(R+agg); Yb=bf16(h@Wrel); R=h@Wroot+b --------
__global__ __launch_bounds__(256) void kA_gather_lin16(
    const int* __restrict__ off_end, const int* __restrict__ csr_src,
    const bf16* __restrict__ Ya, float* __restrict__ R,
    const float* __restrict__ Wrel, const float* __restrict__ bb,
    const float* __restrict__ Wroot, bf16* __restrict__ Yb)
{
    __shared__ float sWrel[HID_F * HID_F];
    __shared__ float sWroot[HID_F * HID_F];
    __shared__ float sb[HID_F];
    if (threadIdx.x < HID_F * HID_F) {
        sWrel[threadIdx.x]  = Wrel[threadIdx.x];
        sWroot[threadIdx.x] = Wroot[threadIdx.x];
    }
    if (threadIdx.x < HID_F) sb[threadIdx.x] = bb[threadIdx.x];
    __syncthreads();

    int t = blockIdx.x * 256 + threadIdx.x;
    int n = t >> 4;
    int lane = t & 15;
    if (n >= N_NODES) return;

    float agg = gather_feat(off_end, csr_src,
                            (const unsigned short*)Ya, n, lane);
    float h = tanhf(R[(size_t)n * HID_F + lane] + agg);

    // Cross-feature matmul within the 16-lane group via shuffles.
    int base = threadIdx.x & 48;   // lane-group base within the wave
    float accR = 0.f, accT = sb[lane];
    #pragma unroll
    for (int k = 0; k < HID_F; ++k) {
        float hk = __shfl(h, base | k);
        accR = fmaf(hk, sWrel[k * HID_F + lane], accR);
        accT = fmaf(hk, sWroot[k * HID_F + lane], accT);
    }

    ((unsigned short*)Yb)[(size_t)n * HID_F + lane] =
        (unsigned short)(__bfloat16_as_ushort(__float2bfloat16(accR)));
    R[(size_t)n * HID_F + lane] = accT;
}

// -------- kB: h2 = tanh(R + gather(Yb)); Ya = bf16(h2) ------------------------
__global__ __launch_bounds__(256) void kB_gather_tanh(
    const int* __restrict__ off_end, const int* __restrict__ csr_src,
    const bf16* __restrict__ Yb, const float* __restrict__ R,
    bf16* __restrict__ Ya)
{
    int t = blockIdx.x * 256 + threadIdx.x;
    int n = t >> 4;
    int lane = t & 15;
    if (n >= N_NODES) return;

    float agg = gather_feat(off_end, csr_src,
                            (const unsigned short*)Yb, n, lane);
    float h2 = tanhf(R[(size_t)n * HID_F + lane] + agg);
    ((unsigned short*)Ya)[(size_t)n * HID_F + lane] =
        (unsigned short)(__bfloat16_as_ushort(__float2bfloat16(h2)));
}

// -------- kC: out = gather(Ya)@W2_rel + b2 + Ya[n]@W2_root --------------------
__global__ __launch_bounds__(256) void kC_gather_out(
    const int* __restrict__ off_end, const int* __restrict__ csr_src,
    const bf16* __restrict__ Ya,
    const float* __restrict__ Wrel, const float* __restrict__ b2,
    const float* __restrict__ Wroot, float* __restrict__ out)
{
    __shared__ float sWrel[HID_F * OUT_F];
    __shared__ float sWroot[HID_F * OUT_F];
    __shared__ float sb[OUT_F];
    for (int i = threadIdx.x; i < HID_F * OUT_F; i += 256) {
        sWrel[i]  = Wrel[i];
        sWroot[i] = Wroot[i];
    }
    if (threadIdx.x < OUT_F) sb[threadIdx.x] = b2[threadIdx.x];
    __syncthreads();

    int t = blockIdx.x * 256 + threadIdx.x;
    int n = t >> 4;
    int lane = t & 15;
    if (n >= N_NODES) return;

    float agg = gather_feat(off_end, csr_src,
                            (const unsigned short*)Ya, n, lane);
    float h2 = bf2f(((const unsigned short*)Ya)[(size_t)n * HID_F + lane]);

    int base = threadIdx.x & 48;
    // Each lane computes output features j = q*16 + lane, q = 0..3 (j < 60).
    float acc[4];
    #pragma unroll
    for (int q = 0; q < 4; ++q) {
        int j = q * 16 + lane;
        acc[q] = (j < OUT_F) ? sb[j] : 0.f;
    }
    #pragma unroll
    for (int k = 0; k < HID_F; ++k) {
        float ak = __shfl(agg, base | k);
        float hk = __shfl(h2,  base | k);
        #pragma unroll
        for (int q = 0; q < 4; ++q) {
            int j = q * 16 + lane;
            if (j < OUT_F) {
                acc[q] = fmaf(ak, sWrel[k * OUT_F + j], acc[q]);
                acc[q] = fmaf(hk, sWroot[k * OUT_F + j], acc[q]);
            }
        }
    }
    float* orow = out + (size_t)n * OUT_F;
    #pragma unroll
    for (int q = 0; q < 4; ++q) {
        int j = q * 16 + lane;
        if (j < OUT_F) orow[j] = acc[q];
    }
}

extern "C" void kernel_launch(void* const* d_in, const int* in_sizes, int n_in,
                              void* d_out, int out_size, void* d_ws, size_t ws_size,
                              hipStream_t stream)
{
    const float* x        = (const float*)d_in[0];
    const int*   ei       = (const int*)d_in[1];
    const float* W1_rel   = (const float*)d_in[2];
    const float* b1       = (const float*)d_in[3];
    const float* W1_root  = (const float*)d_in[4];
    const float* W1b_rel  = (const float*)d_in[5];
    const float* b1b      = (const float*)d_in[6];
    const float* W1b_root = (const float*)d_in[7];
    const float* W2_rel   = (const float*)d_in[8];
    const float* b2       = (const float*)d_in[9];
    const float* W2_root  = (const float*)d_in[10];
    float* out = (float*)d_out;

    const int* src = ei;            // edge_index[0]
    const int* dst = ei + N_EDGES;  // edge_index[1]

    // Workspace (~19.6 MB). pk aliases d_out (consumed in build, before kC).
    bf16* Ya     = (bf16*)d_ws;                           // [N,16] bf16
    bf16* Yb     = Ya + (size_t)N_NODES * HID_F;          // [N,16] bf16
    float* R     = (float*)(Yb + (size_t)N_NODES * HID_F);// [N,16] f32
    int* csr     = (int*)(R + (size_t)N_NODES * HID_F);   // [E]
    int* off_end = csr + N_EDGES;                         // [N]
    int* bcnt    = off_end + N_NODES;                     // [NBKT]
    int* base    = bcnt + NBKT;                           // [NBKT+1]
    int* cursor  = base + NBKT + 1;                       // [NBKT]
    unsigned int* pk = (unsigned int*)d_out;              // [E] scratch

    const int nb_n = (N_NODES + 255) / 256;
    const int nb_g = (N_NODES * HID_F + 255) / 256;       // 6250

    // ---- Build: bucket counting sort -> per-node CSR ----
    k_zero_b<<<1, 1024, 0, stream>>>(bcnt);
    k_bhist<<<NB_H, 256, 0, stream>>>(dst, bcnt);
    k_bscan<<<1, 1024, 0, stream>>>(bcnt, base, cursor);
    k_partition<<<NB_P, 1024, 0, stream>>>(src, dst, cursor, pk);
    k_bucket_csr<<<NBKT, 1024, 0, stream>>>(base, pk, off_end, csr);

    // ---- Layers (fused gather+transform) ----
    k1_lin48<<<nb_n, 256, 0, stream>>>(x, W1_rel, b1, W1_root, Ya, R);
    kA_gather_lin16<<<nb_g, 256, 0, stream>>>(off_end, csr, Ya, R,
                                              W1b_rel, b1b, W1b_root, Yb);
    kB_gather_tanh<<<nb_g, 256, 0, stream>>>(off_end, csr, Yb, R, Ya);
    kC_gather_out<<<nb_g, 256, 0, stream>>>(off_end, csr, Ya,
                                            W2_rel, b2, W2_root, out);
}